// Round 1
// baseline (1857.687 us; speedup 1.0000x reference)
//
#include <hip/hip_runtime.h>

#define N_NODES 100000
#define N_EDGES 1600000
#define IN_F 32
#define OUT_F 64
#define K_TOTAL 25          // 5x5
#define H_ELEMS ((size_t)N_NODES * K_TOTAL * IN_F)   // 80M floats = 320 MB

// degree-1 B-spline basis for one edge: 4 corners (2D), kernel 5x5
__device__ __forceinline__ void edge_basis(const float* __restrict__ pseudo, int e,
                                           float b[4], int k[4]) {
    float v0 = pseudo[e * 2 + 0] * 4.0f;   // (ks-1) = 4
    float v1 = pseudo[e * 2 + 1] * 4.0f;
    int i0 = (int)floorf(v0); i0 = min(max(i0, 0), 3);
    int i1 = (int)floorf(v1); i1 = min(max(i1, 0), 3);
    float f0 = v0 - (float)i0;
    float f1 = v1 - (float)i1;
    float a00 = 1.0f - f0, a01 = f0;       // dim0: amounts[c0]
    float a10 = 1.0f - f1, a11 = f1;       // dim1: amounts[c1]
    // combo order (c0,c1) = (0,0),(0,1),(1,0),(1,1); strides = (5,1)
    b[0] = a00 * a10; k[0] = (i0 + 0) * 5 + (i1 + 0);
    b[1] = a00 * a11; k[1] = (i0 + 0) * 5 + (i1 + 1);
    b[2] = a01 * a10; k[2] = (i0 + 1) * 5 + (i1 + 0);
    b[3] = a01 * a11; k[3] = (i0 + 1) * 5 + (i1 + 1);
}

// ---------------- Two-phase path (needs 320 MB workspace) ----------------

// Phase A: one thread per (edge, in-feature). 4 atomicAdds into H.
__global__ __launch_bounds__(256) void spline_scatter(
        const float* __restrict__ x, const float* __restrict__ pseudo,
        const int* __restrict__ ei, float* __restrict__ H) {
    int tid = blockIdx.x * 256 + threadIdx.x;
    int e = tid >> 5;
    int i = tid & 31;
    if (e >= N_EDGES) return;
    int row = ei[e];
    int col = ei[N_EDGES + e];
    float b[4]; int k[4];
    edge_basis(pseudo, e, b, k);
    float xv = x[col * IN_F + i];
    int base = row * (K_TOTAL * IN_F);
#pragma unroll
    for (int s = 0; s < 4; ++s) {
        atomicAdd(&H[base + k[s] * IN_F + i], b[s] * xv);
    }
}

// Phase B: out[n,o] = bias[o] + sum_j H[n,j] * W[j,o],  j in [0,800)
// Block = 256 threads = 4 waves; block covers 16 nodes (wave w -> nodes 4w..4w+3,
// register-blocked 4 nodes per thread). H rows staged in LDS (16*800 f32 = 51.2 KB).
__global__ __launch_bounds__(256) void spline_gemm(
        const float* __restrict__ H, const float* __restrict__ W,
        const float* __restrict__ bias, float* __restrict__ out) {
    __shared__ float lds[16 * 800];
    const int t = threadIdx.x;
    const int o = t & 63;
    const int w = t >> 6;                 // wave id 0..3
    const size_t nodeBase = (size_t)blockIdx.x * 16;

    // cooperative load: 16 contiguous H rows = 12800 floats = 3200 float4
    const float4* __restrict__ Hsrc = (const float4*)(H + nodeBase * 800);
    float4* L4 = (float4*)lds;
    for (int j = t; j < 3200; j += 256) L4[j] = Hsrc[j];
    __syncthreads();

    const float* __restrict__ h = lds + (w * 4) * 800;
    float bo = bias[o];
    float acc0 = bo, acc1 = bo, acc2 = bo, acc3 = bo;

    for (int j = 0; j < 800; j += 4) {
        float4 h0 = *(const float4*)(h + 0 * 800 + j);
        float4 h1 = *(const float4*)(h + 1 * 800 + j);
        float4 h2 = *(const float4*)(h + 2 * 800 + j);
        float4 h3 = *(const float4*)(h + 3 * 800 + j);
        float w0 = W[(j + 0) * 64 + o];
        float w1 = W[(j + 1) * 64 + o];
        float w2 = W[(j + 2) * 64 + o];
        float w3 = W[(j + 3) * 64 + o];
        acc0 += h0.x * w0 + h0.y * w1 + h0.z * w2 + h0.w * w3;
        acc1 += h1.x * w0 + h1.y * w1 + h1.z * w2 + h1.w * w3;
        acc2 += h2.x * w0 + h2.y * w1 + h2.z * w2 + h2.w * w3;
        acc3 += h3.x * w0 + h3.y * w1 + h3.z * w2 + h3.w * w3;
    }
    float* op = out + (nodeBase + w * 4) * 64 + o;
    op[0 * 64] = acc0;
    op[1 * 64] = acc1;
    op[2 * 64] = acc2;
    op[3 * 64] = acc3;
}

// ---------------- Fallback direct path (no workspace) ----------------

__global__ __launch_bounds__(256) void bias_init(const float* __restrict__ bias,
                                                 float* __restrict__ out) {
    int idx = blockIdx.x * 256 + threadIdx.x;
    if (idx < N_NODES * OUT_F) out[idx] = bias[idx & 63];
}

// one wave per edge: lane o computes sum_s b_s * (x[col] . W[k_s][:,o]); atomic into out[row]
__global__ __launch_bounds__(256) void spline_direct(
        const float* __restrict__ x, const float* __restrict__ pseudo,
        const int* __restrict__ ei, const float* __restrict__ W,
        float* __restrict__ out) {
    int gtid = blockIdx.x * 256 + threadIdx.x;
    int e = gtid >> 6;
    int lane = threadIdx.x & 63;
    if (e >= N_EDGES) return;
    int row = ei[e];
    int col = ei[N_EDGES + e];
    float b[4]; int k[4];
    edge_basis(pseudo, e, b, k);
    float xv = x[col * IN_F + (lane & 31)];
    float acc = 0.0f;
#pragma unroll
    for (int s = 0; s < 4; ++s) {
        const float* __restrict__ Wk = W + k[s] * (IN_F * OUT_F);
        float part = 0.0f;
#pragma unroll
        for (int i = 0; i < IN_F; ++i) {
            float xi = __shfl(xv, i, 64);
            part += xi * Wk[i * OUT_F + lane];
        }
        acc += b[s] * part;
    }
    atomicAdd(&out[row * OUT_F + lane], acc);
}

extern "C" void kernel_launch(void* const* d_in, const int* in_sizes, int n_in,
                              void* d_out, int out_size, void* d_ws, size_t ws_size,
                              hipStream_t stream) {
    const float* features = (const float*)d_in[0];   // [100000, 32]
    const float* pseudo   = (const float*)d_in[1];   // [1600000, 2]
    const int*   eidx     = (const int*)d_in[2];     // [2, 1600000]
    const float* weight   = (const float*)d_in[3];   // [5,5,32,64] -> [800,64]
    const float* bias     = (const float*)d_in[4];   // [64]
    float* out = (float*)d_out;

    const size_t hbytes = H_ELEMS * sizeof(float);   // 320 MB

    if (ws_size >= hbytes) {
        float* H = (float*)d_ws;
        hipMemsetAsync(H, 0, hbytes, stream);
        {
            long long total = (long long)N_EDGES * 32;
            int blocks = (int)((total + 255) / 256);
            spline_scatter<<<blocks, 256, 0, stream>>>(features, pseudo, eidx, H);
        }
        {
            int blocks = N_NODES / 16;  // 6250, exact
            spline_gemm<<<blocks, 256, 0, stream>>>(H, weight, bias, out);
        }
    } else {
        {
            int blocks = (N_NODES * OUT_F + 255) / 256;
            bias_init<<<blocks, 256, 0, stream>>>(bias, out);
        }
        {
            long long total = (long long)N_EDGES * 64;
            int blocks = (int)((total + 255) / 256);
            spline_direct<<<blocks, 256, 0, stream>>>(features, pseudo, eidx, weight, out);
        }
    }
}

// Round 2
// 595.354 us; speedup vs baseline: 3.1203x; 3.1203x over previous
//
#include <hip/hip_runtime.h>

#define N_NODES 100000
#define N_EDGES 1600000
#define IN_F 32
#define OUT_F 64
#define K_TOTAL 25          // 5x5

// ---- workspace layout (bytes) ----
// cnt     : int[100000]        @ 0
// offs    : int[100000]        @ 400000
// cursor  : int[100000]        @ 800000
// tsums   : int[128]           @ 1200000
// tbase   : int[128]           @ 1200512
// payload :                    @ 1201024  (16B aligned)
#define WS_CNT    0
#define WS_OFFS   400000
#define WS_CURSOR 800000
#define WS_TSUMS  1200000
#define WS_TBASE  1200512
#define WS_PAYLOAD 1201024
#define N_TILES 98            // ceil(100000/1024)

// degree-1 B-spline basis for one edge: 4 corners (2D), kernel 5x5
__device__ __forceinline__ void basis_from(float p0, float p1, float b[4], int k[4]) {
    float v0 = p0 * 4.0f;   // (ks-1) = 4
    float v1 = p1 * 4.0f;
    int i0 = (int)floorf(v0); i0 = min(max(i0, 0), 3);
    int i1 = (int)floorf(v1); i1 = min(max(i1, 0), 3);
    float f0 = v0 - (float)i0;
    float f1 = v1 - (float)i1;
    float a00 = 1.0f - f0, a01 = f0;
    float a10 = 1.0f - f1, a11 = f1;
    b[0] = a00 * a10; k[0] = (i0 + 0) * 5 + (i1 + 0);
    b[1] = a00 * a11; k[1] = (i0 + 0) * 5 + (i1 + 1);
    b[2] = a01 * a10; k[2] = (i0 + 1) * 5 + (i1 + 0);
    b[3] = a01 * a11; k[3] = (i0 + 1) * 5 + (i1 + 1);
}

__device__ __forceinline__ void edge_basis(const float* __restrict__ pseudo, int e,
                                           float b[4], int k[4]) {
    basis_from(pseudo[e * 2 + 0], pseudo[e * 2 + 1], b, k);
}

// ---------------- CSR build ----------------

__global__ __launch_bounds__(256) void zero_cnt(int* __restrict__ cnt) {
    int i = blockIdx.x * 256 + threadIdx.x;
    if (i < N_NODES) cnt[i] = 0;
}

__global__ __launch_bounds__(256) void count_edges(const int* __restrict__ ei,
                                                   int* __restrict__ cnt) {
    int e = blockIdx.x * 256 + threadIdx.x;   // grid exactly covers N_EDGES
    atomicAdd(&cnt[ei[e]], 1);
}

// per-1024 tile: exclusive scan within tile -> offs, tile total -> tsums
__global__ __launch_bounds__(256) void scan_tiles(const int* __restrict__ cnt,
                                                  int* __restrict__ offs,
                                                  int* __restrict__ tsums) {
    __shared__ int s[256];
    int t = threadIdx.x;
    int base = blockIdx.x * 1024 + t * 4;
    int c[4];
#pragma unroll
    for (int m = 0; m < 4; ++m) {
        int i = base + m;
        c[m] = (i < N_NODES) ? cnt[i] : 0;
    }
    int tsum = c[0] + c[1] + c[2] + c[3];
    s[t] = tsum;
    __syncthreads();
    for (int d = 1; d < 256; d <<= 1) {
        int v = (t >= d) ? s[t - d] : 0;
        __syncthreads();
        s[t] += v;
        __syncthreads();
    }
    int run = (t > 0) ? s[t - 1] : 0;   // exclusive within tile
#pragma unroll
    for (int m = 0; m < 4; ++m) {
        int i = base + m;
        if (i < N_NODES) offs[i] = run;
        run += c[m];
    }
    if (t == 255) tsums[blockIdx.x] = s[255];
}

__global__ __launch_bounds__(128) void scan_sums(const int* __restrict__ tsums,
                                                 int* __restrict__ tbase) {
    __shared__ int s[128];
    int t = threadIdx.x;
    int v0 = (t < N_TILES) ? tsums[t] : 0;
    s[t] = v0;
    __syncthreads();
    for (int d = 1; d < 128; d <<= 1) {
        int v = (t >= d) ? s[t - d] : 0;
        __syncthreads();
        s[t] += v;
        __syncthreads();
    }
    tbase[t] = (t > 0) ? s[t - 1] : 0;
}

__global__ __launch_bounds__(256) void finalize_offs(int* __restrict__ offs,
                                                     const int* __restrict__ tbase,
                                                     int* __restrict__ cursor) {
    int i = blockIdx.x * 256 + threadIdx.x;
    if (i < N_NODES) {
        int o = offs[i] + tbase[i >> 10];
        offs[i] = o;
        cursor[i] = o;
    }
}

// REC=1: payload = float4 records (col_as_float, p0, p1, 0); REC=0: payload = edge ids
template <int REC>
__global__ __launch_bounds__(256) void fill_csr(const int* __restrict__ ei,
                                                const float* __restrict__ pseudo,
                                                int* __restrict__ cursor,
                                                void* __restrict__ payload) {
    int e = blockIdx.x * 256 + threadIdx.x;   // grid exactly covers N_EDGES
    int row = ei[e];
    int pos = atomicAdd(&cursor[row], 1);
    if (REC) {
        float2 p = *(const float2*)(pseudo + 2 * e);
        float4 r;
        r.x = __int_as_float(ei[N_EDGES + e]);
        r.y = p.x; r.z = p.y; r.w = 0.0f;
        ((float4*)payload)[pos] = r;
    } else {
        ((int*)payload)[pos] = e;
    }
}

// ---------------- fused gather-accumulate + GEMM ----------------
// block = 256 threads, 16 nodes/block. LDS H[16][25*32] = 51.2 KB.
// Accumulate: thread t -> node nn=t>>4, feature pair fp=t&15 (features 2fp,2fp+1).
// GEMM: thread t -> o=t&63, wave w=t>>6 handles nodes 4w..4w+3.
template <int REC>
__global__ __launch_bounds__(256, 1) void fused_spline(
        const float* __restrict__ x, const float* __restrict__ pseudo,
        const int* __restrict__ ei, const float* __restrict__ W,
        const float* __restrict__ bias, const int* __restrict__ offs,
        const int* __restrict__ cnt, const void* __restrict__ payload,
        float* __restrict__ out) {
    __shared__ float Hs[16 * 800];
    const int t = threadIdx.x;

    // zero H
    float4* L4 = (float4*)Hs;
    for (int i = t; i < 3200; i += 256) L4[i] = make_float4(0.f, 0.f, 0.f, 0.f);
    __syncthreads();

    // ---- accumulate edges into LDS H ----
    {
        const int nn = t >> 4;
        const int fp = t & 15;
        const int n = blockIdx.x * 16 + nn;          // grid*16 == N_NODES exactly
        const int start = offs[n];
        const int num = cnt[n];
        float* __restrict__ hb = Hs + nn * 800 + 2 * fp;

        if (REC) {
            const float4* __restrict__ recs = (const float4*)payload;
            float4 nxt; float2 xnxt;
            if (num > 0) {
                nxt = recs[start];
                xnxt = *(const float2*)(x + (size_t)__float_as_int(nxt.x) * IN_F + 2 * fp);
            }
            for (int idx = 0; idx < num; ++idx) {
                float4 cur = nxt; float2 xv = xnxt;
                if (idx + 1 < num) {
                    nxt = recs[start + idx + 1];
                    xnxt = *(const float2*)(x + (size_t)__float_as_int(nxt.x) * IN_F + 2 * fp);
                }
                float b[4]; int k[4];
                basis_from(cur.y, cur.z, b, k);
#pragma unroll
                for (int s = 0; s < 4; ++s) {
                    float2* p = (float2*)(hb + k[s] * IN_F);
                    float2 v = *p;
                    v.x += b[s] * xv.x;
                    v.y += b[s] * xv.y;
                    *p = v;
                }
            }
        } else {
            const int* __restrict__ ids = (const int*)payload;
            int en; float2 pn, xnxt;
            if (num > 0) {
                en = ids[start];
                pn = *(const float2*)(pseudo + 2 * en);
                int cn = ei[N_EDGES + en];
                xnxt = *(const float2*)(x + (size_t)cn * IN_F + 2 * fp);
            }
            for (int idx = 0; idx < num; ++idx) {
                float2 pc = pn; float2 xv = xnxt;
                if (idx + 1 < num) {
                    en = ids[start + idx + 1];
                    pn = *(const float2*)(pseudo + 2 * en);
                    int cn = ei[N_EDGES + en];
                    xnxt = *(const float2*)(x + (size_t)cn * IN_F + 2 * fp);
                }
                float b[4]; int k[4];
                basis_from(pc.x, pc.y, b, k);
#pragma unroll
                for (int s = 0; s < 4; ++s) {
                    float2* p = (float2*)(hb + k[s] * IN_F);
                    float2 v = *p;
                    v.x += b[s] * xv.x;
                    v.y += b[s] * xv.y;
                    *p = v;
                }
            }
        }
    }
    __syncthreads();

    // ---- GEMM: out[16 x 64] = H[16 x 800] * W[800 x 64] + bias ----
    {
        const int o = t & 63;
        const int w = t >> 6;
        const float* __restrict__ h = Hs + (w * 4) * 800;
        float bo = bias[o];
        float acc0 = bo, acc1 = bo, acc2 = bo, acc3 = bo;

        for (int j = 0; j < 800; j += 4) {
            float4 h0 = *(const float4*)(h + 0 * 800 + j);
            float4 h1 = *(const float4*)(h + 1 * 800 + j);
            float4 h2 = *(const float4*)(h + 2 * 800 + j);
            float4 h3 = *(const float4*)(h + 3 * 800 + j);
            float w0 = W[(j + 0) * 64 + o];
            float w1 = W[(j + 1) * 64 + o];
            float w2 = W[(j + 2) * 64 + o];
            float w3 = W[(j + 3) * 64 + o];
            acc0 += h0.x * w0 + h0.y * w1 + h0.z * w2 + h0.w * w3;
            acc1 += h1.x * w0 + h1.y * w1 + h1.z * w2 + h1.w * w3;
            acc2 += h2.x * w0 + h2.y * w1 + h2.z * w2 + h2.w * w3;
            acc3 += h3.x * w0 + h3.y * w1 + h3.z * w2 + h3.w * w3;
        }
        float* op = out + ((size_t)blockIdx.x * 16 + w * 4) * 64 + o;
        op[0 * 64] = acc0;
        op[1 * 64] = acc1;
        op[2 * 64] = acc2;
        op[3 * 64] = acc3;
    }
}

// ---------------- Fallback direct path (tiny/no workspace) ----------------

__global__ __launch_bounds__(256) void bias_init(const float* __restrict__ bias,
                                                 float* __restrict__ out) {
    int idx = blockIdx.x * 256 + threadIdx.x;
    if (idx < N_NODES * OUT_F) out[idx] = bias[idx & 63];
}

__global__ __launch_bounds__(256) void spline_direct(
        const float* __restrict__ x, const float* __restrict__ pseudo,
        const int* __restrict__ ei, const float* __restrict__ W,
        float* __restrict__ out) {
    int gtid = blockIdx.x * 256 + threadIdx.x;
    int e = gtid >> 6;
    int lane = threadIdx.x & 63;
    if (e >= N_EDGES) return;
    int row = ei[e];
    int col = ei[N_EDGES + e];
    float b[4]; int k[4];
    edge_basis(pseudo, e, b, k);
    float xv = x[col * IN_F + (lane & 31)];
    float acc = 0.0f;
#pragma unroll
    for (int s = 0; s < 4; ++s) {
        const float* __restrict__ Wk = W + k[s] * (IN_F * OUT_F);
        float part = 0.0f;
#pragma unroll
        for (int i = 0; i < IN_F; ++i) {
            float xi = __shfl(xv, i, 64);
            part += xi * Wk[i * OUT_F + lane];
        }
        acc += b[s] * part;
    }
    atomicAdd(&out[row * OUT_F + lane], acc);
}

extern "C" void kernel_launch(void* const* d_in, const int* in_sizes, int n_in,
                              void* d_out, int out_size, void* d_ws, size_t ws_size,
                              hipStream_t stream) {
    const float* features = (const float*)d_in[0];   // [100000, 32]
    const float* pseudo   = (const float*)d_in[1];   // [1600000, 2]
    const int*   eidx     = (const int*)d_in[2];     // [2, 1600000]
    const float* weight   = (const float*)d_in[3];   // [5,5,32,64] -> [800,64]
    const float* bias     = (const float*)d_in[4];   // [64]
    float* out = (float*)d_out;

    char* ws = (char*)d_ws;
    int*  cnt    = (int*)(ws + WS_CNT);
    int*  offs   = (int*)(ws + WS_OFFS);
    int*  cursor = (int*)(ws + WS_CURSOR);
    int*  tsums  = (int*)(ws + WS_TSUMS);
    int*  tbase  = (int*)(ws + WS_TBASE);
    void* payload = (void*)(ws + WS_PAYLOAD);

    const size_t needRec = (size_t)WS_PAYLOAD + (size_t)N_EDGES * 16;  // ~26.8 MB
    const size_t needIds = (size_t)WS_PAYLOAD + (size_t)N_EDGES * 4;   // ~7.6 MB

    if (ws_size >= needIds) {
        const int nodeBlocks = (N_NODES + 255) / 256;   // 391
        zero_cnt<<<nodeBlocks, 256, 0, stream>>>(cnt);
        count_edges<<<N_EDGES / 256, 256, 0, stream>>>(eidx, cnt);
        scan_tiles<<<N_TILES, 256, 0, stream>>>(cnt, offs, tsums);
        scan_sums<<<1, 128, 0, stream>>>(tsums, tbase);
        finalize_offs<<<nodeBlocks, 256, 0, stream>>>(offs, tbase, cursor);
        if (ws_size >= needRec) {
            fill_csr<1><<<N_EDGES / 256, 256, 0, stream>>>(eidx, pseudo, cursor, payload);
            fused_spline<1><<<N_NODES / 16, 256, 0, stream>>>(
                features, pseudo, eidx, weight, bias, offs, cnt, payload, out);
        } else {
            fill_csr<0><<<N_EDGES / 256, 256, 0, stream>>>(eidx, pseudo, cursor, payload);
            fused_spline<0><<<N_NODES / 16, 256, 0, stream>>>(
                features, pseudo, eidx, weight, bias, offs, cnt, payload, out);
        }
    } else {
        int blocks = (N_NODES * OUT_F + 255) / 256;
        bias_init<<<blocks, 256, 0, stream>>>(bias, out);
        long long total = (long long)N_EDGES * 64;
        spline_direct<<<(int)((total + 255) / 256), 256, 0, stream>>>(
            features, pseudo, eidx, weight, out);
    }
}